// Round 3
// baseline (429.753 us; speedup 1.0000x reference)
//
#include <hip/hip_runtime.h>
#include <math.h>

#define NROWS 8192
#define DDIM  2048
#define NEXP  4096
#define TK    8

typedef float f4 __attribute__((ext_vector_type(4)));

// Fused: fp64-accumulated dual projection + outer-sum expand + top8 + softmax.
// 256 blocks x 256 threads; block owns 32 rows.
__global__ __launch_bounds__(256) void pkr_fused(const float* __restrict__ x,
                                                 const float* __restrict__ w1,
                                                 const float* __restrict__ w2,
                                                 float* __restrict__ out) {
  __shared__ float  xs[32][36];    // [k][row]  stride 36 -> 16B-aligned f4 reads
  __shared__ float  ws[32][132];   // [k][col]  stride 132 -> 16B-aligned f4 reads
  __shared__ double S[32][128];    // per-block projection results (fp64)

  const int tid   = threadIdx.x;
  const int rows0 = blockIdx.x * 32;

  // ---------------- Phase A: S[r][c] = sum_k x[r][k] * W[c][k] in fp64 -------
  const int rh = tid >> 5;   // 0..7  -> rows rh*4..+3
  const int ch = tid & 31;   // 0..31 -> cols ch*4..+3

  double acc[4][4];
#pragma unroll
  for (int a = 0; a < 4; ++a)
#pragma unroll
    for (int b = 0; b < 4; ++b) acc[a][b] = 0.0;

  const int sxr = tid >> 3;          // 0..31 (row for x staging)
  const int sxk = (tid & 7) * 4;     // 0..28 (k quad)
  const float* xrow = x + (size_t)(rows0 + sxr) * DDIM + sxk;

  for (int k0 = 0; k0 < DDIM; k0 += 32) {
    // stage x tile (32 rows x 32 k): one float4 per thread, transposed into LDS
    f4 xv = *(const f4*)(xrow + k0);
#pragma unroll
    for (int q = 0; q < 4; ++q) xs[sxk + q][sxr] = xv[q];
    // stage W tile (128 cols x 32 k): four float4 per thread
#pragma unroll
    for (int i = 0; i < 4; ++i) {
      const int idx4 = i * 256 + tid;
      const int c  = idx4 >> 3;          // 0..127
      const int kk = (idx4 & 7) * 4;     // 0..28
      const float* wr = (c < 64) ? (w1 + (size_t)c * DDIM)
                                 : (w2 + (size_t)(c - 64) * DDIM);
      f4 wvv = *(const f4*)(wr + k0 + kk);
#pragma unroll
      for (int q = 0; q < 4; ++q) ws[kk + q][c] = wvv[q];
    }
    __syncthreads();

#pragma unroll 4
    for (int k = 0; k < 32; ++k) {
      f4 xq = *(const f4*)&xs[k][rh * 4];
      f4 wq = *(const f4*)&ws[k][ch * 4];
      double xd[4], wd[4];
#pragma unroll
      for (int a = 0; a < 4; ++a) { xd[a] = (double)xq[a]; wd[a] = (double)wq[a]; }
#pragma unroll
      for (int a = 0; a < 4; ++a)
#pragma unroll
        for (int b = 0; b < 4; ++b)
          acc[a][b] += xd[a] * wd[b];
    }
    __syncthreads();
  }

  // deposit S
#pragma unroll
  for (int a = 0; a < 4; ++a)
#pragma unroll
    for (int b = 0; b < 4; ++b)
      S[rh * 4 + a][ch * 4 + b] = acc[a][b];
  __syncthreads();

  // ---------------- Phase B: per-wave expand + top8 + softmax ----------------
  const int wv   = tid >> 6;   // 0..3
  const int lane = tid & 63;

  float* const outIdx = out;
  float* const outP   = out + (size_t)NROWS * TK;
  float* const outS   = out + (size_t)2 * NROWS * TK;

  for (int q8 = 0; q8 < 8; ++q8) {
    const int rl  = wv * 8 + q8;
    const int row = rows0 + rl;

    const double s1 = S[rl][lane];
    const double s2 = S[rl][64 + lane];

    // ---- write scores[row][i*64+j] = s1[i] + s2[j] (fp32), coalesced ----
    {
      const int il = lane >> 4;          // 0..3
      const int jq = (lane & 15) * 4;    // 0..60
      float* srow = outS + (size_t)row * NEXP;
      const double sj0 = S[rl][64 + jq + 0];
      const double sj1 = S[rl][64 + jq + 1];
      const double sj2 = S[rl][64 + jq + 2];
      const double sj3 = S[rl][64 + jq + 3];
#pragma unroll
      for (int i0 = 0; i0 < 64; i0 += 4) {
        const double si = S[rl][i0 + il];
        f4 v;
        v[0] = (float)(si + sj0);
        v[1] = (float)(si + sj1);
        v[2] = (float)(si + sj2);
        v[3] = (float)(si + sj3);
        *(f4*)(srow + (size_t)(i0 + il) * 64 + jq) = v;
      }
    }

    // ---- top8 of s1 (value desc, index asc) ----
    double av[8]; int ai[8];
    {
      double cur = s1;
#pragma unroll
      for (int t = 0; t < 8; ++t) {
        double bv = cur; int bi = lane;
#pragma unroll
        for (int off = 32; off; off >>= 1) {
          double ov = __shfl_xor(bv, off);
          int    oi = __shfl_xor(bi, off);
          if (ov > bv || (ov == bv && oi < bi)) { bv = ov; bi = oi; }
        }
        av[t] = bv; ai[t] = bi;
        if (lane == bi) cur = -INFINITY;
      }
    }
    // ---- top8 of s2 ----
    double bv8[8]; int bi8[8];
    {
      double cur = s2;
#pragma unroll
      for (int t = 0; t < 8; ++t) {
        double bv = cur; int bi = lane;
#pragma unroll
        for (int off = 32; off; off >>= 1) {
          double ov = __shfl_xor(bv, off);
          int    oi = __shfl_xor(bi, off);
          if (ov > bv || (ov == bv && oi < bi)) { bv = ov; bi = oi; }
        }
        bv8[t] = bv; bi8[t] = bi;
        if (lane == bi) cur = -INFINITY;
      }
    }
    // ---- top8 of 64 candidate sums (tiebreak: flat index asc) ----
    const double cval = av[lane >> 3] + bv8[lane & 7];
    const int    cidx = ai[lane >> 3] * 64 + bi8[lane & 7];
    double vvv[8]; int vidx[8];
    {
      double cur = cval;
#pragma unroll
      for (int t = 0; t < 8; ++t) {
        double bv = cur; int bi = cidx;
#pragma unroll
        for (int off = 32; off; off >>= 1) {
          double ov = __shfl_xor(bv, off);
          int    oi = __shfl_xor(bi, off);
          if (ov > bv || (ov == bv && oi < bi)) { bv = ov; bi = oi; }
        }
        vvv[t] = bv; vidx[t] = bi;
        if (cidx == bi) cur = -INFINITY;   // flat idx unique among candidates
      }
    }

    // ---- softmax + emit ----
    if (lane == 0) {
      float e[8], sum = 0.f;
#pragma unroll
      for (int t = 0; t < 8; ++t) {
        e[t] = expf((float)(vvv[t] - vvv[0]));
        sum += e[t];
      }
      const float inv = 1.0f / sum;
#pragma unroll
      for (int t = 0; t < 8; ++t) {
        outIdx[(size_t)row * TK + t] = (float)vidx[t];
        outP  [(size_t)row * TK + t] = e[t] * inv;
      }
    }
  }
}

extern "C" void kernel_launch(void* const* d_in, const int* in_sizes, int n_in,
                              void* d_out, int out_size, void* d_ws, size_t ws_size,
                              hipStream_t stream) {
  const float* x  = (const float*)d_in[0];
  const float* w1 = (const float*)d_in[1];
  const float* w2 = (const float*)d_in[2];
  float* out = (float*)d_out;

  hipLaunchKernelGGL(pkr_fused, dim3(NROWS / 32), dim3(256), 0, stream,
                     x, w1, w2, out);
}

// Round 4
// 296.767 us; speedup vs baseline: 1.4481x; 1.4481x over previous
//
#include <hip/hip_runtime.h>
#include <math.h>

#define NROWS 8192
#define DDIM  2048
#define NEXP  4096
#define TK    8
#define KSPLIT 4
#define KRANGE (DDIM / KSPLIT)   // 512
#define RB     32                // rows per block (kernel 1)

typedef float  f4 __attribute__((ext_vector_type(4)));
typedef double d2 __attribute__((ext_vector_type(2)));

// ---------------- Kernel 1: fp64 partial GEMM, K-split 4 ----------------
// grid 1024 = 256 row-blocks x 4 K-parts; block 256 thr; 32x128 tile, 4x4/thread.
// Partial P[kp] (fp64, 1KB) stored in the front 4KB of each row's score slot.
__global__ __launch_bounds__(256, 4) void pkr_gemm64(const float* __restrict__ x,
                                                     const float* __restrict__ w1,
                                                     const float* __restrict__ w2,
                                                     float* __restrict__ out) {
  __shared__ double xsd[32][34];   // [k][row], stride 34 -> 16B-aligned d2 reads
  __shared__ float  wsf[32][132];  // [k][col], stride 132 -> 16B-aligned f4 reads

  const int tid   = threadIdx.x;
  const int rb    = blockIdx.x >> 2;
  const int kp    = blockIdx.x & 3;
  const int rows0 = rb * RB;
  const int kbase = kp * KRANGE;

  const int rh = tid >> 5;   // 0..7  -> rows rh*4..+3
  const int ch = tid & 31;   // 0..31 -> cols ch*4..+3

  const int sxr = tid >> 3;          // 0..31
  const int sxk = (tid & 7) * 4;     // 0..28
  const float* xrow = x + (size_t)(rows0 + sxr) * DDIM + kbase + sxk;

  double acc[4][4] = {};

  for (int cch = 0; cch < KRANGE / 32; ++cch) {   // 16 chunks of K=32
    const int k0 = cch * 32;
    // stage x tile (32 rows x 32 k), transposed, converted to double once
    f4 xv = *(const f4*)(xrow + k0);
#pragma unroll
    for (int q = 0; q < 4; ++q) xsd[sxk + q][sxr] = (double)xv[q];
    // stage W tile (128 cols x 32 k), raw float
#pragma unroll
    for (int i = 0; i < 4; ++i) {
      const int idx = i * 256 + tid;
      const int c2  = idx >> 3;          // 0..127
      const int kk  = (idx & 7) * 4;     // 0..28
      const float* wr = (c2 < 64) ? (w1 + (size_t)c2 * DDIM)
                                  : (w2 + (size_t)(c2 - 64) * DDIM);
      f4 wv = *(const f4*)(wr + kbase + k0 + kk);
#pragma unroll
      for (int q = 0; q < 4; ++q) wsf[kk + q][c2] = wv[q];
    }
    __syncthreads();

#pragma unroll
    for (int k = 0; k < 32; ++k) {
      const d2 x01 = *(const d2*)&xsd[k][rh * 4];
      const d2 x23 = *(const d2*)&xsd[k][rh * 4 + 2];
      const f4 wq  = *(const f4*)&wsf[k][ch * 4];
      const double xd[4] = { x01[0], x01[1], x23[0], x23[1] };
      double wd[4];
#pragma unroll
      for (int b = 0; b < 4; ++b) wd[b] = (double)wq[b];
#pragma unroll
      for (int a = 0; a < 4; ++a)
#pragma unroll
        for (int b = 0; b < 4; ++b)
          acc[a][b] += xd[a] * wd[b];
    }
    __syncthreads();
  }

  double* P = (double*)(out + (size_t)2 * NROWS * TK);
#pragma unroll
  for (int a = 0; a < 4; ++a) {
    double* dst = P + (size_t)(rows0 + rh * 4 + a) * (NEXP / 2) + kp * 128 + ch * 4;
    d2 lo; lo[0] = acc[a][0]; lo[1] = acc[a][1];
    d2 hi; hi[0] = acc[a][2]; hi[1] = acc[a][3];
    *(d2*)dst       = lo;
    *(d2*)(dst + 2) = hi;
  }
}

// ---------------- Kernel 2: combine partials + expand + top8 + softmax ----------
// One 64-lane wave per row (8192 blocks).
__global__ __launch_bounds__(64) void pkr_finish(float* __restrict__ out) {
  const int row  = blockIdx.x;
  const int lane = threadIdx.x;

  const double* Pr = (const double*)(out + (size_t)2 * NROWS * TK) + (size_t)row * (NEXP / 2);
  double s1 = 0.0, s2 = 0.0;
#pragma unroll
  for (int p = 0; p < KSPLIT; ++p) {
    s1 += Pr[p * 128 + lane];
    s2 += Pr[p * 128 + 64 + lane];
  }

  __shared__ double sh1[64], sh2[64];
  sh1[lane] = s1;
  sh2[lane] = s2;
  __syncthreads();   // memory fence: all partial reads precede slot overwrite

  // ---- scores[row][i*64+j] = (float)(s1[i] + s2[j]), coalesced 1KB/inst ----
  {
    float* srow = out + (size_t)2 * NROWS * TK + (size_t)row * NEXP;
    const int il = lane >> 4;          // 0..3
    const int jq = (lane & 15) * 4;    // 0..60
    const double sj0 = sh2[jq + 0], sj1 = sh2[jq + 1];
    const double sj2 = sh2[jq + 2], sj3 = sh2[jq + 3];
#pragma unroll
    for (int i0 = 0; i0 < 64; i0 += 4) {
      const double si = sh1[i0 + il];
      f4 v;
      v[0] = (float)(si + sj0);
      v[1] = (float)(si + sj1);
      v[2] = (float)(si + sj2);
      v[3] = (float)(si + sj3);
      *(f4*)(srow + (size_t)(i0 + il) * 64 + jq) = v;
    }
  }

  // ---- top8 of s1 (value desc, index asc) ----
  double av[8]; int ai[8];
  {
    double cur = s1;
#pragma unroll
    for (int t = 0; t < 8; ++t) {
      double bv = cur; int bi = lane;
#pragma unroll
      for (int off = 32; off; off >>= 1) {
        double ov = __shfl_xor(bv, off);
        int    oi = __shfl_xor(bi, off);
        if (ov > bv || (ov == bv && oi < bi)) { bv = ov; bi = oi; }
      }
      av[t] = bv; ai[t] = bi;
      if (lane == bi) cur = -INFINITY;
    }
  }
  // ---- top8 of s2 ----
  double bv8[8]; int bi8[8];
  {
    double cur = s2;
#pragma unroll
    for (int t = 0; t < 8; ++t) {
      double bv = cur; int bi = lane;
#pragma unroll
      for (int off = 32; off; off >>= 1) {
        double ov = __shfl_xor(bv, off);
        int    oi = __shfl_xor(bi, off);
        if (ov > bv || (ov == bv && oi < bi)) { bv = ov; bi = oi; }
      }
      bv8[t] = bv; bi8[t] = bi;
      if (lane == bi) cur = -INFINITY;
    }
  }
  // ---- top8 of 64 candidate sums (tiebreak: flat index asc) ----
  const double cval = av[lane >> 3] + bv8[lane & 7];
  const int    cidx = ai[lane >> 3] * 64 + bi8[lane & 7];
  double vvv[8]; int vidx[8];
  {
    double cur = cval;
#pragma unroll
    for (int t = 0; t < 8; ++t) {
      double bv = cur; int bi = cidx;
#pragma unroll
      for (int off = 32; off; off >>= 1) {
        double ov = __shfl_xor(bv, off);
        int    oi = __shfl_xor(bi, off);
        if (ov > bv || (ov == bv && oi < bi)) { bv = ov; bi = oi; }
      }
      vvv[t] = bv; vidx[t] = bi;
      if (cidx == bi) cur = -INFINITY;   // flat idx unique among candidates
    }
  }

  // ---- softmax + emit ----
  if (lane == 0) {
    float e[8], sum = 0.f;
#pragma unroll
    for (int t = 0; t < 8; ++t) { e[t] = expf((float)(vvv[t] - vvv[0])); sum += e[t]; }
    const float inv = 1.0f / sum;
#pragma unroll
    for (int t = 0; t < 8; ++t) {
      out[(size_t)row * TK + t]                       = (float)vidx[t];
      out[(size_t)NROWS * TK + (size_t)row * TK + t]  = e[t] * inv;
    }
  }
}

extern "C" void kernel_launch(void* const* d_in, const int* in_sizes, int n_in,
                              void* d_out, int out_size, void* d_ws, size_t ws_size,
                              hipStream_t stream) {
  const float* x  = (const float*)d_in[0];
  const float* w1 = (const float*)d_in[1];
  const float* w2 = (const float*)d_in[2];
  float* out = (float*)d_out;

  hipLaunchKernelGGL(pkr_gemm64, dim3((NROWS / RB) * KSPLIT), dim3(256), 0, stream,
                     x, w1, w2, out);
  hipLaunchKernelGGL(pkr_finish, dim3(NROWS), dim3(64), 0, stream, out);
}